// Round 2
// baseline (123.227 us; speedup 1.0000x reference)
//
#include <hip/hip_runtime.h>

// B=32, C=128, H=W=32, kern=2 -> pooled h=w=16
// Fused: avgpool + var + z + pairwise Gaussian mixture log-densities + reduction.
// out = B * sum_{i,c,h,w} [ log(mean_j dA(i,j)+eps) - log(mean_j dB(i,j)+eps) ]
//
// 2-param form: s = sqrt(log2e/(2 var)), then
//   d(i,j) = (1/sqrt(v_j)) exp(-(z-mu_j)^2/(2 v_j)) = 1.17741002*s_j * exp2(-(z-mu_j)^2 * s_j^2)
// The 1.17741002 and the 1/32 mixture mean fold into one scalar applied after the j-sum.
// LDS: two j's packed per float4 {s0,mu0,s1,mu1} -> 16 broadcast b128 reads per pixel
// (halves the LDS-pipe cycles vs the 3-param float4-per-j layout).

#define GKL_EPS 1e-6f

__global__ __launch_bounds__(256) void gkl_main(
    const float* __restrict__ muA, const float* __restrict__ lvA,
    const float* __restrict__ muB, const float* __restrict__ lvB,
    const float* __restrict__ eps, double* __restrict__ ws)
{
    // floats: Q side A [0,1024) + pad, side B [1028,2052) + pad, zs [2056,2600), wsum [2600,2604)
    // Q layout per side: [jpair 16][pixel 16][4] = {s(2jj), mu(2jj), s(2jj+1), mu(2jj+1)}
    // side stride 1028 floats => +4 bank shift so the two half-wave broadcast
    // addresses hit disjoint banks.
    __shared__ float sh[2*1028 + 32*17 + 4];

    const int bid = blockIdx.x;        // 0..2047 = C*16
    const int c   = bid >> 4;
    const int h   = bid & 15;
    const int t   = threadIdx.x;
    const int w   = t & 15;
    const int b0  = t >> 4;
    const int row0 = 2*h, col0 = 2*w;

    // ---- Phase 1: pooled params (each thread: 2 batch rows, both sides) ----
    #pragma unroll
    for (int rep = 0; rep < 2; ++rep) {
        const int b = b0 + rep*16;
        const size_t base = ((size_t)(b*128 + c)*32 + row0)*32 + col0;
        const int qidx = ((b >> 1)*16 + w)*4 + (b & 1)*2;   // float offset in Q

        // side A
        float2 m0 = *(const float2*)(muA + base);
        float2 m1 = *(const float2*)(muA + base + 32);
        float2 l0 = *(const float2*)(lvA + base);
        float2 l1 = *(const float2*)(lvA + base + 32);
        float mu  = (m0.x + m0.y + m1.x + m1.y) * 0.25f;
        float var = (__expf(l0.x) + __expf(l0.y) + __expf(l1.x) + __expf(l1.y)) * 0.0625f;
        float s   = __builtin_amdgcn_sqrtf(0.72134752f * __builtin_amdgcn_rcpf(var));
        *(float2*)(sh + qidx) = make_float2(s, mu);
        float ev = eps[((b*128 + c)*16 + h)*16 + w];
        sh[2*1028 + b*17 + w] = fmaf(__builtin_amdgcn_sqrtf(var), ev, mu);  // z

        // side B
        float2 n0 = *(const float2*)(muB + base);
        float2 n1 = *(const float2*)(muB + base + 32);
        float2 k0 = *(const float2*)(lvB + base);
        float2 k1 = *(const float2*)(lvB + base + 32);
        float mub  = (n0.x + n0.y + n1.x + n1.y) * 0.25f;
        float varb = (__expf(k0.x) + __expf(k0.y) + __expf(k1.x) + __expf(k1.y)) * 0.0625f;
        float sb   = __builtin_amdgcn_sqrtf(0.72134752f * __builtin_amdgcn_rcpf(varb));
        *(float2*)(sh + 1028 + qidx) = make_float2(sb, mub);
    }
    __syncthreads();

    // ---- Phase 2: wave-per-pixel pairwise loop, 2 j's per b128 broadcast ----
    const int lane = t & 63;
    const int wv   = t >> 6;           // wave 0..3
    const int i    = lane & 31;        // sample index
    const int side = lane >> 5;        // 0 = mixture A, 1 = mixture B
    const float4* __restrict__ Qs = (const float4*)(sh + side*1028);
    const float* __restrict__ zp  = sh + 2*1028;
    float* __restrict__ wsum      = sh + 2*1028 + 32*17;

    float tot = 0.f;
    #pragma unroll
    for (int q = 0; q < 4; ++q) {
        const int p  = wv*4 + q;       // pixel for this wave
        const float zi = zp[i*17 + p]; // 17-stride: conflict-free column read
        float acc0 = 0.f, acc1 = 0.f;
        #pragma unroll
        for (int jj = 0; jj < 16; ++jj) {
            float4 f = Qs[jj*16 + p];  // wave-uniform per half -> broadcast
            float d0 = zi - f.y, d1 = zi - f.w;
            float s0 = f.x,      s1 = f.z;
            acc0 = fmaf(s0, exp2f(-(d0*d0*(s0*s0))), acc0);
            acc1 = fmaf(s1, exp2f(-(d1*d1*(s1*s1))), acc1);
        }
        // 1.17741002 (=sqrt(2 ln2)) / 32 = 0.036794063
        float lg = __logf(fmaf(acc0 + acc1, 0.036794063f, GKL_EPS));
        tot += side ? -lg : lg;
    }

    #pragma unroll
    for (int o = 32; o; o >>= 1) tot += __shfl_xor(tot, o, 64);
    if (lane == 0) wsum[wv] = tot;
    __syncthreads();
    if (t == 0)
        ws[bid] = (double)wsum[0] + (double)wsum[1] + (double)wsum[2] + (double)wsum[3];
}

__global__ __launch_bounds__(256) void gkl_final(
    const double* __restrict__ ws, float* __restrict__ out)
{
    __shared__ double part[4];
    const int t = threadIdx.x;
    double s = 0.0;
    for (int k = t; k < 2048; k += 256) s += ws[k];
    #pragma unroll
    for (int o = 32; o; o >>= 1) s += __shfl_xor(s, o, 64);
    if ((t & 63) == 0) part[t >> 6] = s;
    __syncthreads();
    if (t == 0) out[0] = (float)(32.0 * (part[0] + part[1] + part[2] + part[3]));
}

extern "C" void kernel_launch(void* const* d_in, const int* in_sizes, int n_in,
                              void* d_out, int out_size, void* d_ws, size_t ws_size,
                              hipStream_t stream) {
    const float* muA = (const float*)d_in[0];
    const float* lvA = (const float*)d_in[1];
    const float* muB = (const float*)d_in[2];
    const float* lvB = (const float*)d_in[3];
    const float* ep  = (const float*)d_in[4];
    double* ws = (double*)d_ws;          // 2048 doubles = 16 KB
    float* out = (float*)d_out;

    gkl_main<<<2048, 256, 0, stream>>>(muA, lvA, muB, lvB, ep, ws);
    gkl_final<<<1, 256, 0, stream>>>(ws, out);
}